// Round 4
// baseline (225.740 us; speedup 1.0000x reference)
//
#include <hip/hip_runtime.h>
#include <hip/hip_bf16.h>
#include <stdint.h>

typedef __attribute__((ext_vector_type(8))) short short8;
typedef __attribute__((ext_vector_type(4))) float floatx4;

#define FEAT_DIM 1536
#define QD 64
#define NROWS 8192
#define TT 513

__device__ __forceinline__ unsigned short f2bf(float x) {
  union { float f; unsigned u; } t; t.f = x;
  unsigned r = t.u + 0x7fffu + ((t.u >> 16) & 1u);
  return (unsigned short)(r >> 16);
}
__device__ __forceinline__ float bf2f(unsigned short u) {
  union { float f; unsigned u; } t; t.u = ((unsigned)u) << 16;
  return t.f;
}

// K0: proj [1536][64] fp32 -> pbt [64][1536] bf16 (k-contiguous rows for B-frags)
__global__ __launch_bounds__(256) void k_projt(const float* __restrict__ proj,
                                               unsigned short* __restrict__ pbt) {
  int k = blockIdx.x * 256 + threadIdx.x;  // 0..1535
  int n = blockIdx.y;                      // 0..63
  pbt[n * FEAT_DIM + k] = f2bf(proj[k * QD + n]);
}

// K1: sf partials. Block = (16-row tile, K-slice of 384); 4 waves split the slice
// (96 each = 3 MFMA k-steps). Grid 2048 -> 8 blocks/CU for HBM MLP.
// Writes fp32 partial [js][8192][64] -> k_sf2 reduces.
__global__ __launch_bounds__(256, 4) void k_sf(const float* __restrict__ feat,
                                               const unsigned short* __restrict__ pbt,
                                               float* __restrict__ pwork) {
  const int tid = threadIdx.x;
  const int wave = tid >> 6, lane = tid & 63;
  const int q = lane >> 4, n = lane & 15;
  const int rt = blockIdx.x >> 2, js = blockIdx.x & 3;
  const int rbase = rt * 16;
  const int row = rbase + n;
  const int b = row >> 9, ti = row & 511;
  const float* fb = feat + (size_t)(b * TT + ti) * FEAT_DIM;
  const short8* pb = (const short8*)pbt;
  const int kw = js * 384 + wave * 96;

  floatx4 acc0 = {0,0,0,0}, acc1 = {0,0,0,0}, acc2 = {0,0,0,0}, acc3 = {0,0,0,0};

  const int koff = kw + q * 8;
  floatx4 f0 = *(const floatx4*)(fb + koff);
  floatx4 f1 = *(const floatx4*)(fb + koff + 4);
  floatx4 g0 = *(const floatx4*)(fb + FEAT_DIM + koff);
  floatx4 g1 = *(const floatx4*)(fb + FEAT_DIM + koff + 4);
  const int bi0 = n * 192 + (kw >> 3);

  for (int ks = 0; ks < 3; ++ks) {
    floatx4 nf0, nf1, ng0, ng1;
    if (ks < 2) {
      int ko = koff + (ks + 1) * 32;
      nf0 = *(const floatx4*)(fb + ko);
      nf1 = *(const floatx4*)(fb + ko + 4);
      ng0 = *(const floatx4*)(fb + FEAT_DIM + ko);
      ng1 = *(const floatx4*)(fb + FEAT_DIM + ko + 4);
    }
    int bi = bi0 + ks * 4 + q;
    short8 B0 = pb[bi];
    short8 B1 = pb[bi + 16 * 192];
    short8 B2 = pb[bi + 32 * 192];
    short8 B3 = pb[bi + 48 * 192];
    __builtin_amdgcn_sched_barrier(0);   // pin prefetch issue ahead of compute
    union { unsigned short u[8]; short8 v; } A;
#pragma unroll
    for (int j = 0; j < 4; ++j) A.u[j] = f2bf(0.5f * (f0[j] + g0[j]));
#pragma unroll
    for (int j = 0; j < 4; ++j) A.u[4 + j] = f2bf(0.5f * (f1[j] + g1[j]));
    acc0 = __builtin_amdgcn_mfma_f32_16x16x32_bf16(A.v, B0, acc0, 0, 0, 0);
    acc1 = __builtin_amdgcn_mfma_f32_16x16x32_bf16(A.v, B1, acc1, 0, 0, 0);
    acc2 = __builtin_amdgcn_mfma_f32_16x16x32_bf16(A.v, B2, acc2, 0, 0, 0);
    acc3 = __builtin_amdgcn_mfma_f32_16x16x32_bf16(A.v, B3, acc3, 0, 0, 0);
    if (ks < 2) { f0 = nf0; f1 = nf1; g0 = ng0; g1 = ng1; }
  }

  __shared__ float part[4][16][64];
#pragma unroll
  for (int r = 0; r < 4; ++r) {
    part[wave][q * 4 + r][0 * 16 + n] = acc0[r];
    part[wave][q * 4 + r][1 * 16 + n] = acc1[r];
    part[wave][q * 4 + r][2 * 16 + n] = acc2[r];
    part[wave][q * 4 + r][3 * 16 + n] = acc3[r];
  }
  __syncthreads();
  {
    const int r = tid >> 4;          // 0..15
    const int c0 = (tid & 15) * 4;   // 0..60
    floatx4 v;
#pragma unroll
    for (int j = 0; j < 4; ++j)
      v[j] = part[0][r][c0 + j] + part[1][r][c0 + j] +
             part[2][r][c0 + j] + part[3][r][c0 + j];
    *(floatx4*)(pwork + ((size_t)js << 19) + (size_t)(rbase + r) * QD + c0) = v;
  }
}

// K1b: reduce 4 K-slice partials -> bf16 sf + fp32 row-norms sq.
__global__ __launch_bounds__(256) void k_sf2(const float* __restrict__ pwork,
                                             unsigned short* __restrict__ sfb,
                                             float* __restrict__ sq) {
  const int t = blockIdx.x * 256 + threadIdx.x;   // 0..131071
  const int row = t >> 4, c0 = (t & 15) * 4;
  const float* p = pwork + (size_t)row * QD + c0;
  floatx4 v = *(const floatx4*)(p)
            + *(const floatx4*)(p + (1u << 19))
            + *(const floatx4*)(p + (2u << 19))
            + *(const floatx4*)(p + (3u << 19));
  float sqp = 0.0f;
  union { unsigned short u[4]; uint2 d; } P;
#pragma unroll
  for (int j = 0; j < 4; ++j) {
    P.u[j] = f2bf(v[j]);
    float bv = bf2f(P.u[j]);
    sqp += bv * bv;
  }
  *(uint2*)(sfb + (size_t)row * QD + c0) = P.d;
#pragma unroll
  for (int off = 1; off < 16; off <<= 1) sqp += __shfl_xor(sqp, off, 64);
  if ((threadIdx.x & 15) == 0) sq[row] = sqp;
}

// K2: fused pairwise-dot (MFMA) + per-row top-16 via med3 insert net.
// Block = (i-tile of 16) x (j-split of 2048); wave covers 512 j's.
// Single list/lane (live set ~60 VGPR); __launch_bounds__(256,6) -> 85-VGPR
// budget so the list stays in VGPRs (NO AGPR spill - round-3 lesson).
__global__ __launch_bounds__(256, 6) void k_knn(const unsigned short* __restrict__ sfb,
                                                const float* __restrict__ sq,
                                                float* __restrict__ tops) {
  const int tid = threadIdx.x;
  const int wave = tid >> 6, lane = tid & 63;
  const int q = lane >> 4, n = lane & 15;
  const int ib = (blockIdx.x >> 2) * 16;
  const int js = blockIdx.x & 3;
  const short8* sfv = (const short8*)sfb;

  short8 b0 = sfv[(ib + n) * 8 + q];
  short8 b1 = sfv[(ib + n) * 8 + 4 + q];

  float lst[16];
#pragma unroll
  for (int k = 0; k < 16; ++k) lst[k] = 3.0e38f;

  const int j0 = js * 2048 + wave * 512;
  short8 A0 = sfv[(j0 + n) * 8 + q];
  short8 A1 = sfv[(j0 + n) * 8 + 4 + q];
  floatx4 s4 = *(const floatx4*)(sq + j0 + q * 4);

  for (int jt = 0; jt < 512; jt += 16) {
    const int jn = j0 + jt + 16;   // last prefetch overruns into sq region: allocated, discarded
    short8 nA0 = sfv[(jn + n) * 8 + q];
    short8 nA1 = sfv[(jn + n) * 8 + 4 + q];
    floatx4 ns4 = *(const floatx4*)(sq + jn + q * 4);
    __builtin_amdgcn_sched_barrier(0);   // pin prefetch issue before compute

    floatx4 acc = {0, 0, 0, 0};
    acc = __builtin_amdgcn_mfma_f32_16x16x32_bf16(A0, b0, acc, 0, 0, 0);
    acc = __builtin_amdgcn_mfma_f32_16x16x32_bf16(A1, b1, acc, 0, 0, 0);

#pragma unroll
    for (int r = 0; r < 4; ++r) {
      float c = fmaf(-2.0f, acc[r], s4[r]);   // key = sq_j - 2*dot (monotone in dist)
#pragma unroll
      for (int k = 15; k >= 1; --k)
        lst[k] = __builtin_amdgcn_fmed3f(lst[k], lst[k - 1], c);
      lst[0] = fminf(lst[0], c);
    }
    A0 = nA0; A1 = nA1; s4 = ns4;
  }

  // f16 keys: 8.7 KB LDS (vs 36 KB fp32) so LDS never caps occupancy.
  __shared__ _Float16 lists[16][16][17];
  const int sl = wave * 4 + q;
#pragma unroll
  for (int k = 0; k < 16; ++k) lists[sl][n][k] = (_Float16)lst[k];
  __syncthreads();

  // Tournament merge: wave w rows 4w..4w+3; 16 lanes per row = 16 sublists.
  const int sub = lane & 15;
  const int rr = wave * 4 + (lane >> 4);
  int p = 0;
  float h = (float)lists[sub][rr][0];
  float* trow = tops + ((size_t)(ib + rr) * 4 + js) * 16;
#pragma unroll 1
  for (int it = 0; it < 16; ++it) {
    float v = h; int idx = sub;
#pragma unroll
    for (int off = 1; off < 16; off <<= 1) {
      float v2 = __shfl_xor(v, off, 64);
      int i2 = __shfl_xor(idx, off, 64);
      if (v2 < v || (v2 == v && i2 < idx)) { v = v2; idx = i2; }
    }
    if (sub == 0) trow[it] = v;
    if (idx == sub) { ++p; h = (float)lists[sub][rr][p]; }
  }
}

// K2b: per row, merge 4 partial top-16s (64 candidates) -> top-16, sqrt-sum, mean.
__global__ __launch_bounds__(256) void k_merge(const float* __restrict__ tops,
                                               const float* __restrict__ sq,
                                               float* __restrict__ intrew,
                                               float* __restrict__ accum) {
  const int tid = threadIdx.x;
  const int wave = tid >> 6, lane = tid & 63;
  const int row = blockIdx.x * 4 + wave;
  float v = tops[(size_t)row * 64 + lane];
  const float sqr = sq[row];
  float sum = 0.0f;
#pragma unroll 1
  for (int it = 0; it < 16; ++it) {
    float m = v; int idx = lane;
#pragma unroll
    for (int off = 1; off < 64; off <<= 1) {
      float v2 = __shfl_xor(m, off, 64);
      int i2 = __shfl_xor(idx, off, 64);
      if (v2 < m || (v2 == m && i2 < idx)) { m = v2; idx = i2; }
    }
    sum += sqrtf(fmaxf(sqr + m, 1e-12f));
    if (lane == idx) v = 3.0e38f;   // remove exactly one winner
  }
  __shared__ float bsum;
  if (tid == 0) bsum = 0.0f;
  __syncthreads();
  if (lane == 0) {
    float ir = sum * (1.0f / 16.0f);
    intrew[row] = ir;
    atomicAdd(&bsum, ir);
  }
  __syncthreads();
  if (tid == 0) atomicAdd(accum, bsum);
}

// K3: StreamNorm + add reward
__global__ __launch_bounds__(256) void k_final(const float* __restrict__ reward,
                                               const float* __restrict__ intrew,
                                               const float* __restrict__ accum,
                                               float* __restrict__ out) {
  int i = blockIdx.x * 256 + threadIdx.x;   // 0..8191
  float mean = accum[0] * (1.0f / 8192.0f);
  float mag = 0.99f + 0.01f * mean;
  int b = i >> 9, ti = i & 511;
  out[i] = reward[b * TT + ti] + intrew[i] / (mag + 1e-8f);
}

extern "C" void kernel_launch(void* const* d_in, const int* in_sizes, int n_in,
                              void* d_out, int out_size, void* d_ws, size_t ws_size,
                              hipStream_t stream) {
  const float* feat   = (const float*)d_in[0];
  const float* reward = (const float*)d_in[1];
  const float* proj   = (const float*)d_in[2];
  float* out = (float*)d_out;

  char* ws = (char*)d_ws;
  unsigned short* sfb = (unsigned short*)ws;                   // 1 MB: sf bf16 [8192][64]
  float* sq           = (float*)(ws + 0x100000);               // 32 KB
  float* intrew       = (float*)(ws + 0x110000);               // 32 KB
  float* accum        = (float*)(ws + 0x120000);               // 4 B
  unsigned short* pbt = (unsigned short*)(ws + 0x130000);      // 192 KB
  float* tops         = (float*)(ws + 0x160000);               // 2 MB: [8192][4][16]
  float* pwork        = (float*)(ws + 0x360000);               // 8 MB: [4][8192][64] fp32

  hipMemsetAsync(accum, 0, sizeof(float), stream);
  k_projt<<<dim3(6, 64), 256, 0, stream>>>(proj, pbt);
  k_sf<<<2048, 256, 0, stream>>>(feat, pbt, pwork);
  k_sf2<<<512, 256, 0, stream>>>(pwork, sfb, sq);
  k_knn<<<2048, 256, 0, stream>>>(sfb, sq, tops);
  k_merge<<<2048, 256, 0, stream>>>(tops, sq, intrew, accum);
  k_final<<<32, 256, 0, stream>>>(reward, intrew, accum, out);
}

// Round 5
// 172.544 us; speedup vs baseline: 1.3083x; 1.3083x over previous
//
#include <hip/hip_runtime.h>
#include <hip/hip_bf16.h>
#include <stdint.h>

typedef __attribute__((ext_vector_type(8))) short short8;
typedef __attribute__((ext_vector_type(4))) float floatx4;

#define FEAT_DIM 1536
#define QD 64
#define NROWS 8192
#define TT 513

__device__ __forceinline__ unsigned short f2bf(float x) {
  union { float f; unsigned u; } t; t.f = x;
  unsigned r = t.u + 0x7fffu + ((t.u >> 16) & 1u);
  return (unsigned short)(r >> 16);
}
__device__ __forceinline__ float bf2f(unsigned short u) {
  union { float f; unsigned u; } t; t.u = ((unsigned)u) << 16;
  return t.f;
}
// monotone float->uint map (order-preserving), low 4 bits freed for an index
__device__ __forceinline__ unsigned packkey(float f, int idx) {
  unsigned x = __float_as_uint(f);
  unsigned m = (unsigned)((int)x >> 31);          // 0xFFFFFFFF if negative
  unsigned u = x ^ (m | 0x80000000u);
  return (u & ~15u) | (unsigned)idx;
}
__device__ __forceinline__ float unpackkey(unsigned u) {
  u &= ~15u;
  unsigned x = (u & 0x80000000u) ? (u ^ 0x80000000u) : ~u;
  return __uint_as_float(x);
}

// K1: sf = win @ proj (MFMA bf16), proj transposed+converted on the fly.
// Block = 16 rows; 4 waves split K (384 each); LDS combine; writes sfb bf16 + sq.
__global__ __launch_bounds__(256, 4) void k_sf(const float* __restrict__ feat,
                                               const float* __restrict__ proj,
                                               unsigned short* __restrict__ sfb,
                                               float* __restrict__ sq) {
  const int tid = threadIdx.x;
  const int wave = tid >> 6, lane = tid & 63;
  const int q = lane >> 4, n = lane & 15;
  const int rbase = blockIdx.x * 16;
  const int row = rbase + n;
  const int b = row >> 9, ti = row & 511;
  const float* fb = feat + (size_t)(b * TT + ti) * FEAT_DIM;
  const int kw = wave * 384;

  floatx4 acc0 = {0,0,0,0}, acc1 = {0,0,0,0}, acc2 = {0,0,0,0}, acc3 = {0,0,0,0};

  int koff = kw + q * 8;
  floatx4 f0 = *(const floatx4*)(fb + koff);
  floatx4 f1 = *(const floatx4*)(fb + koff + 4);
  floatx4 g0 = *(const floatx4*)(fb + FEAT_DIM + koff);
  floatx4 g1 = *(const floatx4*)(fb + FEAT_DIM + koff + 4);

  for (int ks = 0; ks < 12; ++ks) {
    floatx4 nf0, nf1, ng0, ng1;
    if (ks < 11) {
      int ko = kw + (ks + 1) * 32 + q * 8;
      nf0 = *(const floatx4*)(fb + ko);
      nf1 = *(const floatx4*)(fb + ko + 4);
      ng0 = *(const floatx4*)(fb + FEAT_DIM + ko);
      ng1 = *(const floatx4*)(fb + FEAT_DIM + ko + 4);
    }
    // gather B-frags from proj fp32 [1536][64]: element j of frag m = proj[kb+j][n+16m]
    const float* pp = proj + (size_t)(kw + ks * 32 + q * 8) * QD + n;
    union { unsigned short u[8]; short8 v; } B0, B1, B2, B3;
#pragma unroll
    for (int j = 0; j < 8; ++j) {
      B0.u[j] = f2bf(pp[j * QD]);
      B1.u[j] = f2bf(pp[j * QD + 16]);
      B2.u[j] = f2bf(pp[j * QD + 32]);
      B3.u[j] = f2bf(pp[j * QD + 48]);
    }
    __builtin_amdgcn_sched_barrier(0);   // pin prefetch issue ahead of compute
    union { unsigned short u[8]; short8 v; } A;
#pragma unroll
    for (int j = 0; j < 4; ++j) A.u[j] = f2bf(0.5f * (f0[j] + g0[j]));
#pragma unroll
    for (int j = 0; j < 4; ++j) A.u[4 + j] = f2bf(0.5f * (f1[j] + g1[j]));
    acc0 = __builtin_amdgcn_mfma_f32_16x16x32_bf16(A.v, B0.v, acc0, 0, 0, 0);
    acc1 = __builtin_amdgcn_mfma_f32_16x16x32_bf16(A.v, B1.v, acc1, 0, 0, 0);
    acc2 = __builtin_amdgcn_mfma_f32_16x16x32_bf16(A.v, B2.v, acc2, 0, 0, 0);
    acc3 = __builtin_amdgcn_mfma_f32_16x16x32_bf16(A.v, B3.v, acc3, 0, 0, 0);
    if (ks < 11) { f0 = nf0; f1 = nf1; g0 = ng0; g1 = ng1; }
  }

  __shared__ float part[4][16][64];
#pragma unroll
  for (int r = 0; r < 4; ++r) {
    part[wave][q * 4 + r][0 * 16 + n] = acc0[r];
    part[wave][q * 4 + r][1 * 16 + n] = acc1[r];
    part[wave][q * 4 + r][2 * 16 + n] = acc2[r];
    part[wave][q * 4 + r][3 * 16 + n] = acc3[r];
  }
  __syncthreads();
  {
    const int r = tid >> 4;          // 0..15
    const int c0 = (tid & 15) * 4;   // 0..60
    float sqp = 0.0f;
    union { unsigned short u[4]; uint2 d; } P;
#pragma unroll
    for (int j = 0; j < 4; ++j) {
      float v = part[0][r][c0 + j] + part[1][r][c0 + j] +
                part[2][r][c0 + j] + part[3][r][c0 + j];
      P.u[j] = f2bf(v);
      float bv = bf2f(P.u[j]);
      sqp += bv * bv;
    }
    *(uint2*)(sfb + (size_t)(rbase + r) * QD + c0) = P.d;
#pragma unroll
    for (int off = 1; off < 16; off <<= 1) sqp += __shfl_xor(sqp, off, 64);
    if ((tid & 15) == 0) sq[rbase + r] = sqp;
  }
}

// K2: pairwise-dot (MFMA) + per-row top-16 via med3 insert net.
// Block = (i-tile of 32) x (j-split of 2048); wave covers 512 j's; lane owns TWO
// i-lists. __launch_bounds__(256,4): 128-reg budget >= ~92 live -> lists stay in
// arch VGPRs (R3/R4 lesson: tighter budgets split the unified file and every med3
// pays an extra v_accvgpr_read). Grid 1024 = exactly 4 blocks/CU.
__global__ __launch_bounds__(256, 4) void k_knn(const unsigned short* __restrict__ sfb,
                                                const float* __restrict__ sq,
                                                float* __restrict__ tops) {
  const int tid = threadIdx.x;
  const int wave = tid >> 6, lane = tid & 63;
  const int q = lane >> 4, n = lane & 15;
  const int ib = (blockIdx.x >> 2) * 32;
  const int js = blockIdx.x & 3;
  const short8* sfv = (const short8*)sfb;

  short8 b0 = sfv[(ib + n) * 8 + q];
  short8 b1 = sfv[(ib + n) * 8 + 4 + q];
  short8 b2 = sfv[(ib + 16 + n) * 8 + q];
  short8 b3 = sfv[(ib + 16 + n) * 8 + 4 + q];

  float lst0[16], lst1[16];
#pragma unroll
  for (int k = 0; k < 16; ++k) { lst0[k] = 3.0e38f; lst1[k] = 3.0e38f; }

  const int j0 = js * 2048 + wave * 512;
  short8 A0 = sfv[(j0 + n) * 8 + q];
  short8 A1 = sfv[(j0 + n) * 8 + 4 + q];
  floatx4 s4 = *(const floatx4*)(sq + j0 + q * 4);

  for (int jt = 0; jt < 512; jt += 16) {
    const int jn = j0 + jt + 16;   // final prefetch overruns into ws scratch: allocated, discarded
    short8 nA0 = sfv[(jn + n) * 8 + q];
    short8 nA1 = sfv[(jn + n) * 8 + 4 + q];
    floatx4 ns4 = *(const floatx4*)(sq + jn + q * 4);
    __builtin_amdgcn_sched_barrier(0);   // pin prefetch issue before compute

    floatx4 acc0 = {0, 0, 0, 0};
    acc0 = __builtin_amdgcn_mfma_f32_16x16x32_bf16(A0, b0, acc0, 0, 0, 0);
    acc0 = __builtin_amdgcn_mfma_f32_16x16x32_bf16(A1, b1, acc0, 0, 0, 0);
    floatx4 acc1 = {0, 0, 0, 0};
    acc1 = __builtin_amdgcn_mfma_f32_16x16x32_bf16(A0, b2, acc1, 0, 0, 0);
    acc1 = __builtin_amdgcn_mfma_f32_16x16x32_bf16(A1, b3, acc1, 0, 0, 0);

#pragma unroll
    for (int r = 0; r < 4; ++r) {
      float c = fmaf(-2.0f, acc0[r], s4[r]);   // key = sq_j - 2*dot (monotone in dist)
#pragma unroll
      for (int k = 15; k >= 1; --k)
        lst0[k] = __builtin_amdgcn_fmed3f(lst0[k], lst0[k - 1], c);
      lst0[0] = fminf(lst0[0], c);
    }
#pragma unroll
    for (int r = 0; r < 4; ++r) {
      float c = fmaf(-2.0f, acc1[r], s4[r]);
#pragma unroll
      for (int k = 15; k >= 1; --k)
        lst1[k] = __builtin_amdgcn_fmed3f(lst1[k], lst1[k - 1], c);
      lst1[0] = fminf(lst1[0], c);
    }
    A0 = nA0; A1 = nA1; s4 = ns4;
  }

  // packed sortable keys (low 4 bits = sublist id) -> 1-shuffle tournament steps
  __shared__ unsigned lists[16][32][17];
  const int sl = wave * 4 + q;
#pragma unroll
  for (int k = 0; k < 16; ++k) {
    lists[sl][n][k] = packkey(lst0[k], sl);
    lists[sl][n + 16][k] = packkey(lst1[k], sl);
  }
  __syncthreads();

  const int sub = lane & 15;
#pragma unroll 1
  for (int pass = 0; pass < 2; ++pass) {
    const int rr = pass * 16 + wave * 4 + (lane >> 4);
    int p = 0;
    unsigned h = lists[sub][rr][0];
    float* trow = tops + ((size_t)(ib + rr) * 4 + js) * 16;
#pragma unroll 1
    for (int it = 0; it < 16; ++it) {
      unsigned u = h;
#pragma unroll
      for (int off = 1; off < 16; off <<= 1) {
        unsigned u2 = __shfl_xor(u, off, 64);
        u = (u2 < u) ? u2 : u;
      }
      if (sub == 0) trow[it] = unpackkey(u);
      if ((u & 15u) == (unsigned)sub) { ++p; h = lists[sub][rr][p]; }
    }
  }
}

// K2b: one THREAD per row. LDS-staged coalesced load of the row's 64 candidates,
// serial med3 re-insert (all in VGPRs, fully unrolled), sqrt-sum, per-block psum.
__global__ __launch_bounds__(256) void k_merge(const float* __restrict__ tops,
                                               const float* __restrict__ sq,
                                               float* __restrict__ intrew,
                                               float* __restrict__ psum) {
  const int tid = threadIdx.x;
  __shared__ float buf[256][65];
  const size_t base = (size_t)blockIdx.x * 256 * 64;
#pragma unroll 1
  for (int j = 0; j < 64; ++j) {
    int f = j * 256 + tid;
    buf[f >> 6][f & 63] = tops[base + f];
  }
  __syncthreads();

  float l[16];
#pragma unroll
  for (int k = 0; k < 16; ++k) l[k] = 3.0e38f;
#pragma unroll 1
  for (int c = 0; c < 64; ++c) {
    float v = buf[tid][c];
#pragma unroll
    for (int k = 15; k >= 1; --k)
      l[k] = __builtin_amdgcn_fmed3f(l[k], l[k - 1], v);
    l[0] = fminf(l[0], v);
  }
  const int row = blockIdx.x * 256 + tid;
  const float sqr = sq[row];
  float sum = 0.0f;
#pragma unroll
  for (int k = 0; k < 16; ++k) sum += sqrtf(fmaxf(sqr + l[k], 1e-12f));
  float ir = sum * (1.0f / 16.0f);
  intrew[row] = ir;

  // block reduction -> psum[block]
  float w = ir;
#pragma unroll
  for (int off = 1; off < 64; off <<= 1) w += __shfl_xor(w, off, 64);
  __shared__ float ws4[4];
  if ((tid & 63) == 0) ws4[tid >> 6] = w;
  __syncthreads();
  if (tid == 0) psum[blockIdx.x] = ws4[0] + ws4[1] + ws4[2] + ws4[3];
}

// K3: StreamNorm + add reward (psum has 32 block sums; no atomics, no memset)
__global__ __launch_bounds__(256) void k_final(const float* __restrict__ reward,
                                               const float* __restrict__ intrew,
                                               const float* __restrict__ psum,
                                               float* __restrict__ out) {
  int i = blockIdx.x * 256 + threadIdx.x;   // 0..8191
  float total = 0.0f;
#pragma unroll
  for (int k = 0; k < 32; ++k) total += psum[k];
  float mean = total * (1.0f / 8192.0f);
  float mag = 0.99f + 0.01f * mean;
  int b = i >> 9, ti = i & 511;
  out[i] = reward[b * TT + ti] + intrew[i] / (mag + 1e-8f);
}

extern "C" void kernel_launch(void* const* d_in, const int* in_sizes, int n_in,
                              void* d_out, int out_size, void* d_ws, size_t ws_size,
                              hipStream_t stream) {
  const float* feat   = (const float*)d_in[0];
  const float* reward = (const float*)d_in[1];
  const float* proj   = (const float*)d_in[2];
  float* out = (float*)d_out;

  char* ws = (char*)d_ws;
  unsigned short* sfb = (unsigned short*)ws;                   // 1 MB: sf bf16 [8192][64]
  float* sq           = (float*)(ws + 0x100000);               // 32 KB
  float* intrew       = (float*)(ws + 0x110000);               // 32 KB
  float* psum         = (float*)(ws + 0x120000);               // 128 B
  float* tops         = (float*)(ws + 0x160000);               // 2 MB: [8192][4][16]

  k_sf<<<512, 256, 0, stream>>>(feat, proj, sfb, sq);
  k_knn<<<1024, 256, 0, stream>>>(sfb, sq, tops);
  k_merge<<<32, 256, 0, stream>>>(tops, sq, intrew, psum);
  k_final<<<32, 256, 0, stream>>>(reward, intrew, psum, out);
}